// Round 1
// baseline (117.204 us; speedup 1.0000x reference)
//
#include <hip/hip_runtime.h>

// NodeEdgeProjection: out[b, e, f] = x[b, e/127, f]
// B=128, N=128 nodes, n_edges = 128*127 = 16256, F=64, fp32.
// permutations(range(N),2) lexicographic order => receiver idx[e] = e / (N-1).
// Pure streaming gather: ~533 MB write, 4 MB read (cache-resident). Write-BW bound.

constexpr unsigned Bn  = 128;
constexpr unsigned Nn  = 128;
constexpr unsigned Fn  = 64;
constexpr unsigned NE  = Nn * (Nn - 1);   // 16256
constexpr unsigned F4  = Fn / 4;          // 16 float4 per feature row
constexpr unsigned TOTAL4 = Bn * NE * F4; // 33,292,288 (< 2^31)

__global__ __launch_bounds__(256) void node_edge_gather(
    const float4* __restrict__ x, float4* __restrict__ out) {
    unsigned stride = gridDim.x * blockDim.x;
    for (unsigned o = blockIdx.x * blockDim.x + threadIdx.x; o < TOTAL4; o += stride) {
        unsigned f4   = o & (F4 - 1);      // o % 16
        unsigned rest = o >> 4;            // o / 16  -> b*NE + e
        unsigned e    = rest % NE;         // compiler magic-mul
        unsigned b    = rest / NE;
        unsigned node = e / (Nn - 1);      // receiver node = e / 127 (magic-mul)
        out[o] = x[(b * Nn + node) * F4 + f4];
    }
}

extern "C" void kernel_launch(void* const* d_in, const int* in_sizes, int n_in,
                              void* d_out, int out_size, void* d_ws, size_t ws_size,
                              hipStream_t stream) {
    const float4* x = (const float4*)d_in[0];
    float4* out = (float4*)d_out;

    // Memory-bound: cap grid at ~8 blocks/CU * 256 CUs and grid-stride the rest.
    unsigned threads = 256;
    unsigned blocks = (TOTAL4 + threads - 1) / threads;
    if (blocks > 2048) blocks = 2048;

    node_edge_gather<<<blocks, threads, 0, stream>>>(x, out);
}

// Round 3
// 103.132 us; speedup vs baseline: 1.1365x; 1.1365x over previous
//
#include <hip/hip_runtime.h>

// NodeEdgeProjection: out[b, e, f] = x[b, e/127, f]
// B=128, N=128, n_edges = 128*127 = 16256, F=64, fp32.
// Structure: for each (b, node) pair, replicate one 64-float row 127 times
// into a contiguous 32 KB output span. One block per (b,node):
//   - thread tid caches x[b, node, (tid&15)*4 ..] as a float4 register (1 load)
//   - stores it to rows tid>>4, tid>>4+16, ... (7-8 coalesced nt stores)
// No per-element division, no loads in the store loop. Write-BW bound;
// measured streaming-store ceiling on this chip ~7 TB/s (fillBuffer dispatches).
//
// NOTE: __builtin_nontemporal_store requires a clang vector type, not HIP's
// struct float4 — use ext_vector_type(4) float.

typedef float f32x4 __attribute__((ext_vector_type(4)));

constexpr unsigned Bn = 128;
constexpr unsigned Nn = 128;
constexpr unsigned Fn = 64;
constexpr unsigned NE = Nn * (Nn - 1);  // 16256
constexpr unsigned F4 = Fn / 4;         // 16 float4 per feature row

__global__ __launch_bounds__(256) void node_edge_bcast(
    const f32x4* __restrict__ x, f32x4* __restrict__ out) {
    const unsigned blk  = blockIdx.x;        // = b*Nn + node
    const unsigned tid  = threadIdx.x;
    const unsigned f4   = tid & (F4 - 1);    // feature quad 0..15
    const unsigned row0 = tid >> 4;          // starting replica row 0..15

    // One load per thread; 16 threads share each float4 (L1 broadcast).
    const f32x4 v = x[blk * F4 + f4];

    const unsigned b    = blk >> 7;          // / Nn
    const unsigned node = blk & (Nn - 1);    // % Nn
    f32x4* dst = out + (b * NE + node * (Nn - 1)) * F4;

    // 127 replica rows, strided by 16 across row0. A wave's 64 lanes cover
    // 4 consecutive rows x 16 quads = 4 KB contiguous per iteration.
    #pragma unroll
    for (unsigned r = row0; r < Nn - 1; r += 16) {
        __builtin_nontemporal_store(v, &dst[r * F4 + f4]);
    }
}

extern "C" void kernel_launch(void* const* d_in, const int* in_sizes, int n_in,
                              void* d_out, int out_size, void* d_ws, size_t ws_size,
                              hipStream_t stream) {
    const f32x4* x = (const f32x4*)d_in[0];
    f32x4* out = (f32x4*)d_out;

    node_edge_bcast<<<Bn * Nn, 256, 0, stream>>>(x, out);
}